// Round 16
// baseline (510.719 us; speedup 1.0000x reference)
//
#include <hip/hip_runtime.h>
#include <stdint.h>

typedef unsigned short u16;
typedef __attribute__((ext_vector_type(8))) short bf16x8;
typedef __attribute__((ext_vector_type(4))) float f32x4;
typedef __attribute__((ext_vector_type(4))) unsigned short u16x4;
typedef __attribute__((ext_vector_type(8))) unsigned short u16x8;

#define SCALE_LOG2E 0.12751743007633614f   // 128^-0.5 * log2(e)

__device__ __forceinline__ u16 f2bf(float x){
  uint32_t u = __float_as_uint(x);
  u += 0x7FFFu + ((u >> 16) & 1u);
  return (u16)(u >> 16);
}
__device__ __forceinline__ u16 f2bf_trunc(float x){
  return (u16)(__float_as_uint(x) >> 16);   // 1-op truncation; P in [0,1], err <= 2^-8*P
}
__device__ __forceinline__ float bf2f(u16 h){
  return __uint_as_float(((uint32_t)h) << 16);
}
__device__ __forceinline__ void gload16(const void* g, void* l){
  __builtin_amdgcn_global_load_lds((const __attribute__((address_space(1))) void*)g,
                                   (__attribute__((address_space(3))) void*)l, 16, 0, 0);
}

// ---------------- fused fp32 -> bf16 convert (all 5 tensors, one launch) ----------------
__global__ __launch_bounds__(256) void k_cvt5(
    const float* __restrict__ s0, u16* __restrict__ d0,
    const float* __restrict__ s1, u16* __restrict__ d1,
    const float* __restrict__ s2, u16* __restrict__ d2,
    const float* __restrict__ s3, u16* __restrict__ d3,
    const float* __restrict__ s4, u16* __restrict__ d4)
{
  int b = blockIdx.x;
  const float* s; u16* d; int off;
  if      (b < 8192)  { s=s0; d=d0; off=b; }
  else if (b < 12288) { s=s1; d=d1; off=b-8192; }
  else if (b < 14336) { s=s2; d=d2; off=b-12288; }
  else if (b < 16384) { s=s3; d=d3; off=b-14336; }
  else                { s=s4; d=d4; off=b-16384; }
  size_t i = ((size_t)off * 256 + threadIdx.x) * 4;
  float4 v = *(const float4*)(s + i);
  ushort4 o;
  o.x = f2bf(v.x); o.y = f2bf(v.y); o.z = f2bf(v.z); o.w = f2bf(v.w);
  *(ushort4*)(d + i) = o;
}

// ---------------- 256x256 GEMM, BK=64, 8 waves, 4-phase counted-vmcnt schedule ----------
#define STAGE_UNIT(PTR, ROWOFF, BUF, TENS, KS, T1) do{ \
  _Pragma("unroll") \
  for(int jj=0;jj<2;jj++){ \
    int rs_ = wid*32 + jj*16 + (lane>>2); \
    int kp_ = (lane&3) ^ ((rs_>>1)&3); \
    gload16((PTR) + (size_t)((ROWOFF)+rs_)*K + (size_t)(T1)*64 + (KS)*32 + kp_*8, \
            &lds[BUF][TENS][KS][(wid*2+jj)*512]); \
  }}while(0)

#define FRAG(BASE, ROW) (*(const bf16x8*)((BASE) + (ROW)*32 + ((c_ ^ (((ROW)>>1)&3))<<3)))

__global__ __launch_bounds__(512,2) void k_gemm256(
    const u16* __restrict__ A, const u16* __restrict__ Bw, void* __restrict__ Cout,
    int N, int K, int ldc, int out_f32)
{
  __shared__ u16 lds[2][2][2][256*32];   // 128 KiB
  const int tid = threadIdx.x, wid = tid>>6, lane = tid&63;
  const int nbn = N >> 8;
  const int cpx = gridDim.x >> 3;
  const int bid = (blockIdx.x & 7)*cpx + (blockIdx.x >> 3);
  const int bm = bid / nbn, bn = bid % nbn;
  const int m0 = bm<<8, n0 = bn<<8;
  const int wm = wid>>2, wn = wid&3;
  const int c_ = lane>>4, rl = lane&15;

  f32x4 acc[8][4];
  f32x4 zero4 = {0.f,0.f,0.f,0.f};
#pragma unroll
  for (int i=0;i<8;i++)
#pragma unroll
    for (int j=0;j<4;j++) acc[i][j] = zero4;

  STAGE_UNIT(A,  m0, 0, 0, 0, 0);
  STAGE_UNIT(Bw, n0, 0, 1, 0, 0);
  STAGE_UNIT(A,  m0, 0, 0, 1, 0);
  STAGE_UNIT(Bw, n0, 0, 1, 1, 0);

  const int nt = K >> 6;
#pragma unroll 2
  for (int t=0; t<nt; ++t) {
    const int cur = t&1, nxt = cur^1;
    const bool pf = (t+1 < nt);
    const u16* Ab0 = lds[cur][0][0];
    const u16* Bb0 = lds[cur][1][0];
    const u16* Ab1 = lds[cur][0][1];
    const u16* Bb1 = lds[cur][1][1];
    bf16x8 af[4], bf[4];

    asm volatile("s_waitcnt vmcnt(4)" ::: "memory");
    __builtin_amdgcn_s_barrier();
    asm volatile("" ::: "memory");
#pragma unroll
    for (int j=0;j<4;j++) bf[j] = FRAG(Bb0, wn*64 + j*16 + rl);
#pragma unroll
    for (int i=0;i<4;i++) af[i] = FRAG(Ab0, wm*128 + i*16 + rl);
    if (pf) STAGE_UNIT(A, m0, nxt, 0, 0, t+1);
    __builtin_amdgcn_s_setprio(1);
#pragma unroll
    for (int i=0;i<4;i++)
#pragma unroll
      for (int j=0;j<4;j++)
        acc[i][j] = __builtin_amdgcn_mfma_f32_16x16x32_bf16(af[i], bf[j], acc[i][j], 0,0,0);
    __builtin_amdgcn_s_setprio(0);
    __builtin_amdgcn_s_barrier();
    asm volatile("" ::: "memory");

#pragma unroll
    for (int i=0;i<4;i++) af[i] = FRAG(Ab0, wm*128 + (i+4)*16 + rl);
    if (pf) STAGE_UNIT(Bw, n0, nxt, 1, 0, t+1);
    __builtin_amdgcn_s_setprio(1);
#pragma unroll
    for (int i=0;i<4;i++)
#pragma unroll
      for (int j=0;j<4;j++)
        acc[i+4][j] = __builtin_amdgcn_mfma_f32_16x16x32_bf16(af[i], bf[j], acc[i+4][j], 0,0,0);
    __builtin_amdgcn_s_setprio(0);
    __builtin_amdgcn_s_barrier();
    asm volatile("" ::: "memory");

    if (pf) { asm volatile("s_waitcnt vmcnt(4)" ::: "memory"); }
    else    { asm volatile("s_waitcnt vmcnt(0)" ::: "memory"); }
    __builtin_amdgcn_s_barrier();
    asm volatile("" ::: "memory");
#pragma unroll
    for (int j=0;j<4;j++) bf[j] = FRAG(Bb1, wn*64 + j*16 + rl);
#pragma unroll
    for (int i=0;i<4;i++) af[i] = FRAG(Ab1, wm*128 + i*16 + rl);
    if (pf) STAGE_UNIT(A, m0, nxt, 0, 1, t+1);
    __builtin_amdgcn_s_setprio(1);
#pragma unroll
    for (int i=0;i<4;i++)
#pragma unroll
      for (int j=0;j<4;j++)
        acc[i][j] = __builtin_amdgcn_mfma_f32_16x16x32_bf16(af[i], bf[j], acc[i][j], 0,0,0);
    __builtin_amdgcn_s_setprio(0);
    __builtin_amdgcn_s_barrier();
    asm volatile("" ::: "memory");

#pragma unroll
    for (int i=0;i<4;i++) af[i] = FRAG(Ab1, wm*128 + (i+4)*16 + rl);
    if (pf) STAGE_UNIT(Bw, n0, nxt, 1, 1, t+1);
    __builtin_amdgcn_s_setprio(1);
#pragma unroll
    for (int i=0;i<4;i++)
#pragma unroll
      for (int j=0;j<4;j++)
        acc[i+4][j] = __builtin_amdgcn_mfma_f32_16x16x32_bf16(af[i], bf[j], acc[i+4][j], 0,0,0);
    __builtin_amdgcn_s_setprio(0);
    __builtin_amdgcn_s_barrier();
    asm volatile("" ::: "memory");
  }

  const int r0 = m0 + wm*128 + ((lane>>4)<<2);
  const int c0 = n0 + wn*64 + rl;
  if (out_f32) {
    float* C = (float*)Cout;
#pragma unroll
    for (int i=0;i<8;i++)
#pragma unroll
      for (int j=0;j<4;j++)
#pragma unroll
        for (int r=0;r<4;r++)
          C[(size_t)(r0 + i*16 + r)*ldc + (c0 + j*16)] = acc[i][j][r];
  } else {
    u16* C = (u16*)Cout;
#pragma unroll
    for (int i=0;i<8;i++)
#pragma unroll
      for (int j=0;j<4;j++)
#pragma unroll
        for (int r=0;r<4;r++)
          C[(size_t)(r0 + i*16 + r)*ldc + (c0 + j*16)] = f2bf(acc[i][j][r]);
  }
}

// ---------------- 128x256 GEMM (full-chip Wo): BK=64, 8 waves (2m x 4n), 2-phase ------
#define STAGE_A128(BUF, KS, T1) do{ \
  int rs_ = wid*16 + (lane>>2); \
  int kp_ = (lane&3) ^ ((rs_>>1)&3); \
  gload16(A + (size_t)(m0+rs_)*K + (size_t)(T1)*64 + (KS)*32 + kp_*8, \
          &ldsA[BUF][KS][wid*512]); \
  }while(0)

#define STAGE_B128(BUF, KS, T1) do{ \
  _Pragma("unroll") \
  for(int jj=0;jj<2;jj++){ \
    int rs_ = wid*32 + jj*16 + (lane>>2); \
    int kp_ = (lane&3) ^ ((rs_>>1)&3); \
    gload16(Bw + (size_t)(n0+rs_)*K + (size_t)(T1)*64 + (KS)*32 + kp_*8, \
            &ldsB[BUF][KS][(wid*2+jj)*512]); \
  }}while(0)

__global__ __launch_bounds__(512,2) void k_gemm_bm128(
    const u16* __restrict__ A, const u16* __restrict__ Bw, float* __restrict__ C,
    int N, int K, int ldc)
{
  __shared__ u16 ldsA[2][2][128*32];   // 32 KiB
  __shared__ u16 ldsB[2][2][256*32];   // 64 KiB -> 96 KiB total
  const int tid = threadIdx.x, wid = tid>>6, lane = tid&63;
  const int nbn = N >> 8;
  const int cpx = gridDim.x >> 3;
  const int bid = (blockIdx.x & 7)*cpx + (blockIdx.x >> 3);
  const int bm = bid / nbn, bn = bid % nbn;
  const int m0 = bm<<7, n0 = bn<<8;
  const int wm = wid>>2, wn = wid&3;
  const int c_ = lane>>4, rl = lane&15;

  f32x4 acc[4][4];
  f32x4 zero4 = {0.f,0.f,0.f,0.f};
#pragma unroll
  for (int i=0;i<4;i++)
#pragma unroll
    for (int j=0;j<4;j++) acc[i][j] = zero4;

  STAGE_A128(0, 0, 0);
  STAGE_B128(0, 0, 0);
  STAGE_A128(0, 1, 0);
  STAGE_B128(0, 1, 0);

  const int nt = K >> 6;
#pragma unroll 2
  for (int t=0; t<nt; ++t) {
    const int cur = t&1, nxt = cur^1;
    const bool pf = (t+1 < nt);
    bf16x8 af[4], bf[4];

    asm volatile("s_waitcnt vmcnt(3)" ::: "memory");
    __builtin_amdgcn_s_barrier();
    asm volatile("" ::: "memory");
#pragma unroll
    for (int i=0;i<4;i++) af[i] = FRAG(ldsA[cur][0], wm*64 + i*16 + rl);
#pragma unroll
    for (int j=0;j<4;j++) bf[j] = FRAG(ldsB[cur][0], wn*64 + j*16 + rl);
    if (pf) { STAGE_A128(nxt, 0, t+1); STAGE_B128(nxt, 0, t+1); }
    __builtin_amdgcn_s_setprio(1);
#pragma unroll
    for (int i=0;i<4;i++)
#pragma unroll
      for (int j=0;j<4;j++)
        acc[i][j] = __builtin_amdgcn_mfma_f32_16x16x32_bf16(af[i], bf[j], acc[i][j], 0,0,0);
    __builtin_amdgcn_s_setprio(0);
    __builtin_amdgcn_s_barrier();
    asm volatile("" ::: "memory");

    if (pf) { asm volatile("s_waitcnt vmcnt(3)" ::: "memory"); }
    else    { asm volatile("s_waitcnt vmcnt(0)" ::: "memory"); }
    __builtin_amdgcn_s_barrier();
    asm volatile("" ::: "memory");
#pragma unroll
    for (int i=0;i<4;i++) af[i] = FRAG(ldsA[cur][1], wm*64 + i*16 + rl);
#pragma unroll
    for (int j=0;j<4;j++) bf[j] = FRAG(ldsB[cur][1], wn*64 + j*16 + rl);
    if (pf) { STAGE_A128(nxt, 1, t+1); STAGE_B128(nxt, 1, t+1); }
    __builtin_amdgcn_s_setprio(1);
#pragma unroll
    for (int i=0;i<4;i++)
#pragma unroll
      for (int j=0;j<4;j++)
        acc[i][j] = __builtin_amdgcn_mfma_f32_16x16x32_bf16(af[i], bf[j], acc[i][j], 0,0,0);
    __builtin_amdgcn_s_setprio(0);
    __builtin_amdgcn_s_barrier();
    asm volatile("" ::: "memory");
  }

  const int r0 = m0 + wm*64 + ((lane>>4)<<2);
  const int c0 = n0 + wn*64 + rl;
#pragma unroll
  for (int i=0;i<4;i++)
#pragma unroll
    for (int j=0;j<4;j++)
#pragma unroll
      for (int r=0;r<4;r++)
        C[(size_t)(r0 + i*16 + r)*ldc + (c0 + j*16)] = acc[i][j][r];
}

// ---------------- RMSNorm + RoPE in place on K region of qkv (bf16); Q fused in attn --
__global__ __launch_bounds__(256) void k_normrope_k(
    u16* __restrict__ qkv, const float* __restrict__ cosb, const float* __restrict__ sinb,
    const float* __restrict__ kw)
{
  const int tid = threadIdx.x, lane = tid&63;
  const int task = blockIdx.x*4 + (tid>>6);     // 32768 tasks: bs(4096) x kvh(8)
  const int bs = task >> 3, col = 2048 + (task & 7)*128;
  u16* row = qkv + (size_t)bs*4096 + col;
  float x0 = bf2f(row[lane]), x1 = bf2f(row[lane+64]);
  float ss = x0*x0 + x1*x1;
#pragma unroll
  for (int m=1; m<64; m<<=1) ss += __shfl_xor(ss, m, 64);
  float rn = rsqrtf(ss*(1.0f/128.0f) + 1e-6f);
  const float* cp = cosb + (size_t)bs*128;
  const float* sp = sinb + (size_t)bs*128;
  float q0 = x0*rn*kw[lane], q1 = x1*rn*kw[lane+64];
  float o0 = q0*cp[lane]    - q1*sp[lane];
  float o1 = q1*cp[lane+64] + q0*sp[lane+64];
  row[lane]    = f2bf(o0);
  row[lane+64] = f2bf(o1);
}

// ---------------- transpose V region of qkv -> vt[(b*8+kvh)*128 + d][s] ----------------
__global__ __launch_bounds__(256) void k_vtrans(const u16* __restrict__ qkv, u16* __restrict__ vt)
{
  const int bid = blockIdx.x;
  const int dt = bid & 1, st = (bid>>1)&31, kvh = (bid>>6)&7, b = bid>>9;
  __shared__ u16 tile[64][72];
  const int tid = threadIdx.x;
  const int rr = tid >> 3, c = (tid & 7) * 8;
  const u16* src = qkv + ((size_t)(b*2048 + st*64))*4096 + 3072 + kvh*128 + dt*64;
#pragma unroll
  for (int p=0;p<2;p++){
    int sl = p*32 + rr;
    u16x8 v = *(const u16x8*)(src + (size_t)sl*4096 + c);
#pragma unroll
    for (int e=0;e<8;e++) tile[sl][c+e] = v[e];
  }
  __syncthreads();
  u16* dst = vt + ((size_t)((b*8+kvh)*128 + dt*64))*2048 + st*64;
#pragma unroll
  for (int p=0;p<2;p++){
    int dl = p*32 + rr;
    u16x8 o;
#pragma unroll
    for (int e=0;e<8;e++) o[e] = tile[c+e][dl];
    *(u16x8*)(dst + (size_t)dl*2048 + c) = o;
  }
}

// ---------------- fused causal attention: 8 waves, 16 q-rows/wave, fused Q-norm+RoPE --
#define STAGE_K8(T, DSTBUF) do { \
  _Pragma("unroll") \
  for (int i_=0;i_<2;i_++){ \
    int r_ = wv*8 + i_*4 + (lane>>4); \
    int cs_ = (lane&15) ^ (r_&7); \
    gload16(Kb + (size_t)((T)*64 + r_)*4096 + cs_*8, (DSTBUF) + (wv*2+i_)*512); \
  } } while(0)

#define STAGE_V8(T, DSTBUF) do { \
  _Pragma("unroll") \
  for (int i_=0;i_<2;i_++){ \
    int d_ = wv*16 + i_*8 + (lane>>3); \
    int cs_ = (lane&7) ^ (d_&7); \
    gload16(Vb + (size_t)d_*2048 + (T)*64 + cs_*8, (DSTBUF) + (wv*2+i_)*512); \
  } } while(0)

#define COMPUTE_S16(SACC, KBUF) do { \
  _Pragma("unroll") \
  for (int ks_=0;ks_<4;ks_++){ \
    bf16x8 bfr_[4]; \
    _Pragma("unroll") \
    for (int ns_=0;ns_<4;ns_++){ \
      int n_ = ns_*16 + (lane&15); \
      int sl_ = (ks_*4 + (lane>>4)) ^ (n_&7); \
      bfr_[ns_] = *(const bf16x8*)((KBUF) + n_*128 + sl_*8); \
    } \
    _Pragma("unroll") \
    for (int ns_=0;ns_<4;ns_++) \
      SACC[ns_] = __builtin_amdgcn_mfma_f32_16x16x32_bf16(qf[ks_], bfr_[ns_], SACC[ns_], 0,0,0); \
  } } while(0)

__global__ __launch_bounds__(512,4) void k_attn(
    const u16* __restrict__ qkv, const u16* __restrict__ vt,
    const float* __restrict__ cosb, const float* __restrict__ sinb,
    const float* __restrict__ qw,
    float* __restrict__ probs, u16* __restrict__ attn_o)
{
  __shared__ u16 lKV[4][64*128];  // 64 KiB
  __shared__ u16 lP[8][16*64];    // 16 KiB  -> 80 KiB total, 2 blocks/CU = 4 waves/SIMD
  const int tid = threadIdx.x, wv = tid>>6, lane = tid&63;
  const int rl = lane&15, hi = lane>>4;
  const int bid = blockIdx.x;
  const int r9 = bid >> 5;
  const int qt = (r9 < 8) ? (15 - r9) : (r9 - 8);   // balanced heavy+light pairing
  const int bh = bid & 31;
  const int h = bh & 15, b = bh >> 4;
  const int kvh = h>>1;
  const int q0 = qt<<7;
  const u16* Qb = qkv + (size_t)b*2048*4096 + h*128;
  const u16* Kb = qkv + (size_t)b*2048*4096 + 2048 + kvh*128;
  const u16* Vb = vt + (size_t)(b*8+kvh)*128*2048;

  f32x4 zero4 = {0.f,0.f,0.f,0.f};

  // ---- fused Q RMSNorm + RoPE: this wave's 16 rows (q0 + wv*16 + rl), f32 in regs ----
  bf16x8 qf[4];
  {
    const int srow = q0 + wv*16 + rl;             // global seq row
    float xq[4][8];
    float ss = 0.f;
#pragma unroll
    for (int ks=0;ks<4;ks++){
      bf16x8 raw = *(const bf16x8*)(Qb + (size_t)srow*4096 + ks*32 + hi*8);
#pragma unroll
      for (int j=0;j<8;j++){
        float x = bf2f((u16)raw[j]);
        xq[ks][j] = x;
        ss += x*x;
      }
    }
    ss += __shfl_xor(ss, 16, 64);
    ss += __shfl_xor(ss, 32, 64);
    float rn = rsqrtf(ss*(1.0f/128.0f) + 1e-6f);
    const float* cp = cosb + (size_t)(b*2048 + srow)*128;
    const float* sp = sinb + (size_t)(b*2048 + srow)*128;
#pragma unroll
    for (int ks2=0;ks2<2;ks2++){
#pragma unroll
      for (int j=0;j<8;j++){
        int d0 = ks2*32 + hi*8 + j;               // in [0,64)
        int d1 = d0 + 64;
        float a  = xq[ks2][j]   * rn * qw[d0];
        float bb = xq[ks2+2][j] * rn * qw[d1];
        float o0 = a*cp[d0] - bb*sp[d0];
        float o1 = bb*cp[d1] + a*sp[d1];
        qf[ks2][j]   = (short)f2bf(o0);
        qf[ks2+2][j] = (short)f2bf(o1);
      }
    }
  }

  const int nkt = 2*qt + 2;
  const int tdiag = 2*qt + (wv>>2);   // wave's diagonal tile; waves 0-3 skip final tile
  const int rb = q0 + wv*16 + hi*4;   // this thread's 4 q-rows
  float lsum[4] = {0.f,0.f,0.f,0.f};

  // ---- sweep 1: denominators; quad-buffered K, counted waits, 1 barrier/tile ----
  STAGE_K8(0, lKV[0]);
  STAGE_K8(1, lKV[1]);
  if (nkt > 2) STAGE_K8(2, lKV[2]);
  for (int t=0; t<nkt; ++t) {
    if      (t+2 < nkt) { asm volatile("s_waitcnt vmcnt(4)" ::: "memory"); }
    else if (t+1 < nkt) { asm volatile("s_waitcnt vmcnt(2)" ::: "memory"); }
    else                { asm volatile("s_waitcnt vmcnt(0)" ::: "memory"); }
    __syncthreads();
    if (t+3 < nkt) STAGE_K8(t+3, lKV[(t+3)&3]);
    asm volatile("" ::: "memory");
    if (t <= tdiag) {
      f32x4 sacc[4];
#pragma unroll
      for (int ns=0;ns<4;ns++) sacc[ns] = zero4;
      COMPUTE_S16(sacc, lKV[t&3]);
      const int cb = t*64 + rl;
      if (t == tdiag) {
#pragma unroll
        for (int ns=0;ns<4;ns++)
#pragma unroll
          for (int r=0;r<4;r++){
            int rg = rb + r, cg = cb + ns*16;
            float e = __builtin_exp2f(sacc[ns][r]*SCALE_LOG2E);
            lsum[r] += (cg <= rg) ? e : 0.f;
          }
      } else {
#pragma unroll
        for (int ns=0;ns<4;ns++)
#pragma unroll
          for (int r=0;r<4;r++)
            lsum[r] += __builtin_exp2f(sacc[ns][r]*SCALE_LOG2E);
      }
    }
  }
#pragma unroll
  for (int m=1;m<16;m<<=1)
#pragma unroll
    for (int r=0;r<4;r++) lsum[r] += __shfl_xor(lsum[r], m, 64);
  float Lr[4];
#pragma unroll
  for (int r=0;r<4;r++) Lr[r] = -__log2f(lsum[r]);   // fold 1/lsum into exp2 addend

  // ---- sweep 2: probs + PV; dbuf K+V, counted ledger (4 loads + 4 vec stores/tile) ----
  f32x4 oacc[8];
#pragma unroll
  for (int nd=0;nd<8;nd++) oacc[nd] = zero4;

  u16* pw = lP[wv];
  float* pb = probs + (size_t)bh*2048*2048;

  int cur = 0;
  STAGE_K8(0, lKV[0]);
  STAGE_V8(0, lKV[2]);
  asm volatile("s_waitcnt vmcnt(0)" ::: "memory");
  __syncthreads();
  for (int t=0; t<nkt; ++t) {
    const bool pf = (t+1 < nkt);
    if (pf) { STAGE_K8(t+1, lKV[cur^1]); STAGE_V8(t+1, lKV[2+(cur^1)]); }
    asm volatile("" ::: "memory");   // pin staging loads ahead of prob stores (vmcnt FIFO)
    if (t <= tdiag) {
      f32x4 sacc[4];
#pragma unroll
      for (int ns=0;ns<4;ns++) sacc[ns] = zero4;
      COMPUTE_S16(sacc, lKV[cur]);
      const int cb = t*64 + rl;
      if (t == tdiag) {
#pragma unroll
        for (int ns=0;ns<4;ns++)
#pragma unroll
          for (int r=0;r<4;r++){
            int rg = rb + r, cg = cb + ns*16;
            float p = (cg <= rg) ? __builtin_exp2f(fmaf(sacc[ns][r], SCALE_LOG2E, Lr[r])) : 0.f;
            int ql = hi*4 + r, kl = ns*16 + rl;
            pw[ql*64 + (((kl>>3) ^ (ql&7))<<3) + (kl&7)] = f2bf_trunc(p);
          }
      } else {
#pragma unroll
        for (int ns=0;ns<4;ns++)
#pragma unroll
          for (int r=0;r<4;r++){
            float p = __builtin_exp2f(fmaf(sacc[ns][r], SCALE_LOG2E, Lr[r]));
            int ql = hi*4 + r, kl = ns*16 + rl;
            pw[ql*64 + (((kl>>3) ^ (ql&7))<<3) + (kl&7)] = f2bf_trunc(p);
          }
      }
      // vectorized prob store: read back rows from lP, 4 x dwordx4 nontemporal
      {
        const int cq = rl, grp = cq>>1, off = (cq&1)*4;
#pragma unroll
        for (int it=0; it<4; ++it){
          int row = it*4 + hi;
          int slot = grp ^ (row&7);
          u16x4 pk4 = *(const u16x4*)(pw + row*64 + slot*8 + off);
          f32x4 pf4;
#pragma unroll
          for (int r=0;r<4;r++) pf4[r] = bf2f(pk4[r]);
          __builtin_nontemporal_store(pf4,
            (f32x4*)(pb + (size_t)(q0 + wv*16 + row)*2048 + t*64 + cq*4));
        }
      }
      // PV from lKV[2+cur]
      const u16* vbuf = lKV[2+cur];
#pragma unroll
      for (int kks=0;kks<2;kks++){
        bf16x8 pa;
        {
          int ql = rl;
          int sl = (kks*4 + hi) ^ (ql&7);
          pa = *(const bf16x8*)(pw + ql*64 + sl*8);
        }
#pragma unroll
        for (int nd=0;nd<8;nd++){
          int d = nd*16 + rl;
          int sl = (kks*4 + hi) ^ (d&7);
          bf16x8 vb = *(const bf16x8*)(vbuf + d*64 + sl*8);
          oacc[nd] = __builtin_amdgcn_mfma_f32_16x16x32_bf16(pa, vb, oacc[nd], 0,0,0);
        }
      }
    }
    if (pf) {
      asm volatile("s_waitcnt vmcnt(4)" ::: "memory");
      __syncthreads();
    }
    cur ^= 1;
  }

  // zero-fill strictly-above-diagonal region for this wave's rows
  const int kend = (tdiag+1)*64;
  f32x4 z4 = {0.f,0.f,0.f,0.f};
  for (int q = wv*16; q < wv*16+16; ++q){
    float* rp = pb + (size_t)(q0 + q)*2048;
    for (int c = kend + lane*4; c < 2048; c += 256)
      __builtin_nontemporal_store(z4, (f32x4*)(rp + c));
  }

  // write O (bf16) to workspace in (b, s, h*128+d) layout for the Wo GEMM
#pragma unroll
  for (int nd=0;nd<8;nd++)
#pragma unroll
    for (int r=0;r<4;r++){
      int rg = rb + r;
      int cg = h*128 + nd*16 + rl;
      attn_o[(size_t)(b*2048 + rg)*2048 + cg] = f2bf(oacc[nd][r]);
    }
}

// ---------------- host launch ----------------
extern "C" void kernel_launch(void* const* d_in, const int* in_sizes, int n_in,
                              void* d_out, int out_size, void* d_ws, size_t ws_size,
                              hipStream_t stream) {
  (void)in_sizes; (void)n_in; (void)out_size; (void)ws_size;
  const float* hs   = (const float*)d_in[0];
  const float* cosb = (const float*)d_in[1];
  const float* sinb = (const float*)d_in[2];
  const float* Wq   = (const float*)d_in[4];
  const float* Wk   = (const float*)d_in[5];
  const float* Wv   = (const float*)d_in[6];
  const float* Wo   = (const float*)d_in[7];
  const float* qw   = (const float*)d_in[8];
  const float* kw   = (const float*)d_in[9];
  float* out   = (float*)d_out;
  float* probs = out + 8388608;          // attn_output is 2*2048*2048 floats

  char* ws = (char*)d_ws;
  u16* hs_b   = (u16*)(ws);               // 16 MiB   (aliased: reused as attn_o)
  u16* attn_o = hs_b;
  u16* W_all  = (u16*)(ws + (16u<<20));   // 16 MiB   Wq|Wk|Wv rows (4096 x 2048)
  u16* Wo_b   = (u16*)(ws + (32u<<20));   // 8 MiB
  u16* qkv    = (u16*)(ws + (40u<<20));   // 32 MiB   (4096 x 4096)
  u16* v_t    = (u16*)(ws + (72u<<20));   // 8 MiB    (2*8*128 x 2048)

  k_cvt5<<<20480,256,0,stream>>>(hs, hs_b, Wq, W_all, Wk, W_all + 4194304,
                                 Wv, W_all + 6291456, Wo, Wo_b);

  k_gemm256<<<256,512,0,stream>>>(hs_b, W_all, (void*)qkv, 4096, 2048, 4096, 0);
  k_normrope_k<<<8192,256,0,stream>>>(qkv, cosb, sinb, kw);
  k_vtrans<<<1024,256,0,stream>>>(qkv, v_t);
  // PROBE: launch k_attn twice (idempotent — identical outputs). dur_us minus the
  // round-14 baseline (~319 us) measures the attention kernel's true duration.
  k_attn<<<512,512,0,stream>>>(qkv, v_t, cosb, sinb, qw, probs, attn_o);
  k_attn<<<512,512,0,stream>>>(qkv, v_t, cosb, sinb, qw, probs, attn_o);
  k_gemm_bm128<<<256,512,0,stream>>>(attn_o, Wo_b, out, 2048, 2048, 2048);
}

// Round 17
// 311.409 us; speedup vs baseline: 1.6400x; 1.6400x over previous
//
#include <hip/hip_runtime.h>
#include <stdint.h>

typedef unsigned short u16;
typedef __attribute__((ext_vector_type(8))) short bf16x8;
typedef __attribute__((ext_vector_type(4))) float f32x4;
typedef __attribute__((ext_vector_type(4))) unsigned short u16x4;
typedef __attribute__((ext_vector_type(8))) unsigned short u16x8;

#define SCALE_LOG2E 0.12751743007633614f   // 128^-0.5 * log2(e)

__device__ __forceinline__ u16 f2bf(float x){
  uint32_t u = __float_as_uint(x);
  u += 0x7FFFu + ((u >> 16) & 1u);
  return (u16)(u >> 16);
}
__device__ __forceinline__ u16 f2bf_trunc(float x){
  return (u16)(__float_as_uint(x) >> 16);   // 1-op truncation; P in [0,1], err <= 2^-8*P
}
__device__ __forceinline__ float bf2f(u16 h){
  return __uint_as_float(((uint32_t)h) << 16);
}
__device__ __forceinline__ void gload16(const void* g, void* l){
  __builtin_amdgcn_global_load_lds((const __attribute__((address_space(1))) void*)g,
                                   (__attribute__((address_space(3))) void*)l, 16, 0, 0);
}

// ---------------- fused fp32 -> bf16 convert (all 5 tensors, one launch) ----------------
__global__ __launch_bounds__(256) void k_cvt5(
    const float* __restrict__ s0, u16* __restrict__ d0,
    const float* __restrict__ s1, u16* __restrict__ d1,
    const float* __restrict__ s2, u16* __restrict__ d2,
    const float* __restrict__ s3, u16* __restrict__ d3,
    const float* __restrict__ s4, u16* __restrict__ d4)
{
  int b = blockIdx.x;
  const float* s; u16* d; int off;
  if      (b < 8192)  { s=s0; d=d0; off=b; }
  else if (b < 12288) { s=s1; d=d1; off=b-8192; }
  else if (b < 14336) { s=s2; d=d2; off=b-12288; }
  else if (b < 16384) { s=s3; d=d3; off=b-14336; }
  else                { s=s4; d=d4; off=b-16384; }
  size_t i = ((size_t)off * 256 + threadIdx.x) * 4;
  float4 v = *(const float4*)(s + i);
  ushort4 o;
  o.x = f2bf(v.x); o.y = f2bf(v.y); o.z = f2bf(v.z); o.w = f2bf(v.w);
  *(ushort4*)(d + i) = o;
}

// ---------------- 256x256 GEMM, BK=64, 8 waves, 4-phase counted-vmcnt schedule ----------
#define STAGE_UNIT(PTR, ROWOFF, BUF, TENS, KS, T1) do{ \
  _Pragma("unroll") \
  for(int jj=0;jj<2;jj++){ \
    int rs_ = wid*32 + jj*16 + (lane>>2); \
    int kp_ = (lane&3) ^ ((rs_>>1)&3); \
    gload16((PTR) + (size_t)((ROWOFF)+rs_)*K + (size_t)(T1)*64 + (KS)*32 + kp_*8, \
            &lds[BUF][TENS][KS][(wid*2+jj)*512]); \
  }}while(0)

#define FRAG(BASE, ROW) (*(const bf16x8*)((BASE) + (ROW)*32 + ((c_ ^ (((ROW)>>1)&3))<<3)))

__global__ __launch_bounds__(512,2) void k_gemm256(
    const u16* __restrict__ A, const u16* __restrict__ Bw, void* __restrict__ Cout,
    int N, int K, int ldc, int out_f32)
{
  __shared__ u16 lds[2][2][2][256*32];   // 128 KiB
  const int tid = threadIdx.x, wid = tid>>6, lane = tid&63;
  const int nbn = N >> 8;
  const int cpx = gridDim.x >> 3;
  const int bid = (blockIdx.x & 7)*cpx + (blockIdx.x >> 3);
  const int bm = bid / nbn, bn = bid % nbn;
  const int m0 = bm<<8, n0 = bn<<8;
  const int wm = wid>>2, wn = wid&3;
  const int c_ = lane>>4, rl = lane&15;

  f32x4 acc[8][4];
  f32x4 zero4 = {0.f,0.f,0.f,0.f};
#pragma unroll
  for (int i=0;i<8;i++)
#pragma unroll
    for (int j=0;j<4;j++) acc[i][j] = zero4;

  STAGE_UNIT(A,  m0, 0, 0, 0, 0);
  STAGE_UNIT(Bw, n0, 0, 1, 0, 0);
  STAGE_UNIT(A,  m0, 0, 0, 1, 0);
  STAGE_UNIT(Bw, n0, 0, 1, 1, 0);

  const int nt = K >> 6;
#pragma unroll 2
  for (int t=0; t<nt; ++t) {
    const int cur = t&1, nxt = cur^1;
    const bool pf = (t+1 < nt);
    const u16* Ab0 = lds[cur][0][0];
    const u16* Bb0 = lds[cur][1][0];
    const u16* Ab1 = lds[cur][0][1];
    const u16* Bb1 = lds[cur][1][1];
    bf16x8 af[4], bf[4];

    asm volatile("s_waitcnt vmcnt(4)" ::: "memory");
    __builtin_amdgcn_s_barrier();
    asm volatile("" ::: "memory");
#pragma unroll
    for (int j=0;j<4;j++) bf[j] = FRAG(Bb0, wn*64 + j*16 + rl);
#pragma unroll
    for (int i=0;i<4;i++) af[i] = FRAG(Ab0, wm*128 + i*16 + rl);
    if (pf) STAGE_UNIT(A, m0, nxt, 0, 0, t+1);
    __builtin_amdgcn_s_setprio(1);
#pragma unroll
    for (int i=0;i<4;i++)
#pragma unroll
      for (int j=0;j<4;j++)
        acc[i][j] = __builtin_amdgcn_mfma_f32_16x16x32_bf16(af[i], bf[j], acc[i][j], 0,0,0);
    __builtin_amdgcn_s_setprio(0);
    __builtin_amdgcn_s_barrier();
    asm volatile("" ::: "memory");

#pragma unroll
    for (int i=0;i<4;i++) af[i] = FRAG(Ab0, wm*128 + (i+4)*16 + rl);
    if (pf) STAGE_UNIT(Bw, n0, nxt, 1, 0, t+1);
    __builtin_amdgcn_s_setprio(1);
#pragma unroll
    for (int i=0;i<4;i++)
#pragma unroll
      for (int j=0;j<4;j++)
        acc[i+4][j] = __builtin_amdgcn_mfma_f32_16x16x32_bf16(af[i], bf[j], acc[i+4][j], 0,0,0);
    __builtin_amdgcn_s_setprio(0);
    __builtin_amdgcn_s_barrier();
    asm volatile("" ::: "memory");

    if (pf) { asm volatile("s_waitcnt vmcnt(4)" ::: "memory"); }
    else    { asm volatile("s_waitcnt vmcnt(0)" ::: "memory"); }
    __builtin_amdgcn_s_barrier();
    asm volatile("" ::: "memory");
#pragma unroll
    for (int j=0;j<4;j++) bf[j] = FRAG(Bb1, wn*64 + j*16 + rl);
#pragma unroll
    for (int i=0;i<4;i++) af[i] = FRAG(Ab1, wm*128 + i*16 + rl);
    if (pf) STAGE_UNIT(A, m0, nxt, 0, 1, t+1);
    __builtin_amdgcn_s_setprio(1);
#pragma unroll
    for (int i=0;i<4;i++)
#pragma unroll
      for (int j=0;j<4;j++)
        acc[i][j] = __builtin_amdgcn_mfma_f32_16x16x32_bf16(af[i], bf[j], acc[i][j], 0,0,0);
    __builtin_amdgcn_s_setprio(0);
    __builtin_amdgcn_s_barrier();
    asm volatile("" ::: "memory");

#pragma unroll
    for (int i=0;i<4;i++) af[i] = FRAG(Ab1, wm*128 + (i+4)*16 + rl);
    if (pf) STAGE_UNIT(Bw, n0, nxt, 1, 1, t+1);
    __builtin_amdgcn_s_setprio(1);
#pragma unroll
    for (int i=0;i<4;i++)
#pragma unroll
      for (int j=0;j<4;j++)
        acc[i+4][j] = __builtin_amdgcn_mfma_f32_16x16x32_bf16(af[i], bf[j], acc[i+4][j], 0,0,0);
    __builtin_amdgcn_s_setprio(0);
    __builtin_amdgcn_s_barrier();
    asm volatile("" ::: "memory");
  }

  const int r0 = m0 + wm*128 + ((lane>>4)<<2);
  const int c0 = n0 + wn*64 + rl;
  if (out_f32) {
    float* C = (float*)Cout;
#pragma unroll
    for (int i=0;i<8;i++)
#pragma unroll
      for (int j=0;j<4;j++)
#pragma unroll
        for (int r=0;r<4;r++)
          C[(size_t)(r0 + i*16 + r)*ldc + (c0 + j*16)] = acc[i][j][r];
  } else {
    u16* C = (u16*)Cout;
#pragma unroll
    for (int i=0;i<8;i++)
#pragma unroll
      for (int j=0;j<4;j++)
#pragma unroll
        for (int r=0;r<4;r++)
          C[(size_t)(r0 + i*16 + r)*ldc + (c0 + j*16)] = f2bf(acc[i][j][r]);
  }
}

// ---------------- 128x256 GEMM (full-chip Wo): BK=64, 8 waves (2m x 4n), 2-phase ------
#define STAGE_A128(BUF, KS, T1) do{ \
  int rs_ = wid*16 + (lane>>2); \
  int kp_ = (lane&3) ^ ((rs_>>1)&3); \
  gload16(A + (size_t)(m0+rs_)*K + (size_t)(T1)*64 + (KS)*32 + kp_*8, \
          &ldsA[BUF][KS][wid*512]); \
  }while(0)

#define STAGE_B128(BUF, KS, T1) do{ \
  _Pragma("unroll") \
  for(int jj=0;jj<2;jj++){ \
    int rs_ = wid*32 + jj*16 + (lane>>2); \
    int kp_ = (lane&3) ^ ((rs_>>1)&3); \
    gload16(Bw + (size_t)(n0+rs_)*K + (size_t)(T1)*64 + (KS)*32 + kp_*8, \
            &ldsB[BUF][KS][(wid*2+jj)*512]); \
  }}while(0)

__global__ __launch_bounds__(512,2) void k_gemm_bm128(
    const u16* __restrict__ A, const u16* __restrict__ Bw, float* __restrict__ C,
    int N, int K, int ldc)
{
  __shared__ u16 ldsA[2][2][128*32];   // 32 KiB
  __shared__ u16 ldsB[2][2][256*32];   // 64 KiB -> 96 KiB total
  const int tid = threadIdx.x, wid = tid>>6, lane = tid&63;
  const int nbn = N >> 8;
  const int cpx = gridDim.x >> 3;
  const int bid = (blockIdx.x & 7)*cpx + (blockIdx.x >> 3);
  const int bm = bid / nbn, bn = bid % nbn;
  const int m0 = bm<<7, n0 = bn<<8;
  const int wm = wid>>2, wn = wid&3;
  const int c_ = lane>>4, rl = lane&15;

  f32x4 acc[4][4];
  f32x4 zero4 = {0.f,0.f,0.f,0.f};
#pragma unroll
  for (int i=0;i<4;i++)
#pragma unroll
    for (int j=0;j<4;j++) acc[i][j] = zero4;

  STAGE_A128(0, 0, 0);
  STAGE_B128(0, 0, 0);
  STAGE_A128(0, 1, 0);
  STAGE_B128(0, 1, 0);

  const int nt = K >> 6;
#pragma unroll 2
  for (int t=0; t<nt; ++t) {
    const int cur = t&1, nxt = cur^1;
    const bool pf = (t+1 < nt);
    bf16x8 af[4], bf[4];

    asm volatile("s_waitcnt vmcnt(3)" ::: "memory");
    __builtin_amdgcn_s_barrier();
    asm volatile("" ::: "memory");
#pragma unroll
    for (int i=0;i<4;i++) af[i] = FRAG(ldsA[cur][0], wm*64 + i*16 + rl);
#pragma unroll
    for (int j=0;j<4;j++) bf[j] = FRAG(ldsB[cur][0], wn*64 + j*16 + rl);
    if (pf) { STAGE_A128(nxt, 0, t+1); STAGE_B128(nxt, 0, t+1); }
    __builtin_amdgcn_s_setprio(1);
#pragma unroll
    for (int i=0;i<4;i++)
#pragma unroll
      for (int j=0;j<4;j++)
        acc[i][j] = __builtin_amdgcn_mfma_f32_16x16x32_bf16(af[i], bf[j], acc[i][j], 0,0,0);
    __builtin_amdgcn_s_setprio(0);
    __builtin_amdgcn_s_barrier();
    asm volatile("" ::: "memory");

    if (pf) { asm volatile("s_waitcnt vmcnt(3)" ::: "memory"); }
    else    { asm volatile("s_waitcnt vmcnt(0)" ::: "memory"); }
    __builtin_amdgcn_s_barrier();
    asm volatile("" ::: "memory");
#pragma unroll
    for (int i=0;i<4;i++) af[i] = FRAG(ldsA[cur][1], wm*64 + i*16 + rl);
#pragma unroll
    for (int j=0;j<4;j++) bf[j] = FRAG(ldsB[cur][1], wn*64 + j*16 + rl);
    if (pf) { STAGE_A128(nxt, 1, t+1); STAGE_B128(nxt, 1, t+1); }
    __builtin_amdgcn_s_setprio(1);
#pragma unroll
    for (int i=0;i<4;i++)
#pragma unroll
      for (int j=0;j<4;j++)
        acc[i][j] = __builtin_amdgcn_mfma_f32_16x16x32_bf16(af[i], bf[j], acc[i][j], 0,0,0);
    __builtin_amdgcn_s_setprio(0);
    __builtin_amdgcn_s_barrier();
    asm volatile("" ::: "memory");
  }

  const int r0 = m0 + wm*64 + ((lane>>4)<<2);
  const int c0 = n0 + wn*64 + rl;
#pragma unroll
  for (int i=0;i<4;i++)
#pragma unroll
    for (int j=0;j<4;j++)
#pragma unroll
      for (int r=0;r<4;r++)
        C[(size_t)(r0 + i*16 + r)*ldc + (c0 + j*16)] = acc[i][j][r];
}

// ---------------- merged prep: K-RMSNorm+RoPE (blocks 0..8191) + V transpose (8192..9215)
__global__ __launch_bounds__(256) void k_prep(
    u16* __restrict__ qkv, u16* __restrict__ vt,
    const float* __restrict__ cosb, const float* __restrict__ sinb,
    const float* __restrict__ kw)
{
  __shared__ u16 tile[64][72];
  const int tid = threadIdx.x;
  if (blockIdx.x < 8192) {
    const int lane = tid&63;
    const int task = blockIdx.x*4 + (tid>>6);     // 32768 tasks: bs(4096) x kvh(8)
    const int bs = task >> 3, col = 2048 + (task & 7)*128;
    u16* row = qkv + (size_t)bs*4096 + col;
    float x0 = bf2f(row[lane]), x1 = bf2f(row[lane+64]);
    float ss = x0*x0 + x1*x1;
#pragma unroll
    for (int m=1; m<64; m<<=1) ss += __shfl_xor(ss, m, 64);
    float rn = rsqrtf(ss*(1.0f/128.0f) + 1e-6f);
    const float* cp = cosb + (size_t)bs*128;
    const float* sp = sinb + (size_t)bs*128;
    float q0 = x0*rn*kw[lane], q1 = x1*rn*kw[lane+64];
    float o0 = q0*cp[lane]    - q1*sp[lane];
    float o1 = q1*cp[lane+64] + q0*sp[lane+64];
    row[lane]    = f2bf(o0);
    row[lane+64] = f2bf(o1);
  } else {
    const int bid = blockIdx.x - 8192;
    const int dt = bid & 1, st = (bid>>1)&31, kvh = (bid>>6)&7, b = bid>>9;
    const int rr = tid >> 3, c = (tid & 7) * 8;
    const u16* src = qkv + ((size_t)(b*2048 + st*64))*4096 + 3072 + kvh*128 + dt*64;
#pragma unroll
    for (int p=0;p<2;p++){
      int sl = p*32 + rr;
      u16x8 v = *(const u16x8*)(src + (size_t)sl*4096 + c);
#pragma unroll
      for (int e=0;e<8;e++) tile[sl][c+e] = v[e];
    }
    __syncthreads();
    u16* dst = vt + ((size_t)((b*8+kvh)*128 + dt*64))*2048 + st*64;
#pragma unroll
    for (int p=0;p<2;p++){
      int dl = p*32 + rr;
      u16x8 o;
#pragma unroll
      for (int e=0;e<8;e++) o[e] = tile[c+e][dl];
      *(u16x8*)(dst + (size_t)dl*2048 + c) = o;
    }
  }
}

// ---------------- fused causal attention: 8 waves, 16 q-rows/wave, fused Q-norm+RoPE --
#define STAGE_K8(T, DSTBUF) do { \
  _Pragma("unroll") \
  for (int i_=0;i_<2;i_++){ \
    int r_ = wv*8 + i_*4 + (lane>>4); \
    int cs_ = (lane&15) ^ (r_&7); \
    gload16(Kb + (size_t)((T)*64 + r_)*4096 + cs_*8, (DSTBUF) + (wv*2+i_)*512); \
  } } while(0)

#define STAGE_V8(T, DSTBUF) do { \
  _Pragma("unroll") \
  for (int i_=0;i_<2;i_++){ \
    int d_ = wv*16 + i_*8 + (lane>>3); \
    int cs_ = (lane&7) ^ (d_&7); \
    gload16(Vb + (size_t)d_*2048 + (T)*64 + cs_*8, (DSTBUF) + (wv*2+i_)*512); \
  } } while(0)

#define COMPUTE_S16(SACC, KBUF) do { \
  _Pragma("unroll") \
  for (int ks_=0;ks_<4;ks_++){ \
    bf16x8 bfr_[4]; \
    _Pragma("unroll") \
    for (int ns_=0;ns_<4;ns_++){ \
      int n_ = ns_*16 + (lane&15); \
      int sl_ = (ks_*4 + (lane>>4)) ^ (n_&7); \
      bfr_[ns_] = *(const bf16x8*)((KBUF) + n_*128 + sl_*8); \
    } \
    _Pragma("unroll") \
    for (int ns_=0;ns_<4;ns_++) \
      SACC[ns_] = __builtin_amdgcn_mfma_f32_16x16x32_bf16(qf[ks_], bfr_[ns_], SACC[ns_], 0,0,0); \
  } } while(0)

__global__ __launch_bounds__(512,4) void k_attn(
    const u16* __restrict__ qkv, const u16* __restrict__ vt,
    const float* __restrict__ cosb, const float* __restrict__ sinb,
    const float* __restrict__ qw,
    float* __restrict__ probs, u16* __restrict__ attn_o)
{
  __shared__ u16 lKV[4][64*128];  // 64 KiB
  __shared__ u16 lP[8][16*64];    // 16 KiB  -> 80 KiB total, 2 blocks/CU = 4 waves/SIMD
  const int tid = threadIdx.x, wv = tid>>6, lane = tid&63;
  const int rl = lane&15, hi = lane>>4;
  const int bid = blockIdx.x;
  const int r9 = bid >> 5;
  const int qt = (r9 < 8) ? (15 - r9) : (r9 - 8);   // balanced heavy+light pairing
  const int bh = bid & 31;
  const int h = bh & 15, b = bh >> 4;
  const int kvh = h>>1;
  const int q0 = qt<<7;
  const u16* Qb = qkv + (size_t)b*2048*4096 + h*128;
  const u16* Kb = qkv + (size_t)b*2048*4096 + 2048 + kvh*128;
  const u16* Vb = vt + (size_t)(b*8+kvh)*128*2048;

  f32x4 zero4 = {0.f,0.f,0.f,0.f};

  const int nkt = 2*qt + 2;
  const int tdiag = 2*qt + (wv>>2);   // wave's diagonal tile; waves 0-3 skip final tile
  const int rb = q0 + wv*16 + hi*4;   // this thread's 4 q-rows

  // ---- issue sweep-1 K prefetches FIRST: HBM latency hides under the Q-norm below ----
  STAGE_K8(0, lKV[0]);
  STAGE_K8(1, lKV[1]);
  if (nkt > 2) STAGE_K8(2, lKV[2]);

  // ---- fused Q RMSNorm + RoPE: this wave's 16 rows (q0 + wv*16 + rl), f32 in regs ----
  bf16x8 qf[4];
  {
    const int srow = q0 + wv*16 + rl;             // global seq row
    float xq[4][8];
    float ss = 0.f;
#pragma unroll
    for (int ks=0;ks<4;ks++){
      bf16x8 raw = *(const bf16x8*)(Qb + (size_t)srow*4096 + ks*32 + hi*8);
#pragma unroll
      for (int j=0;j<8;j++){
        float x = bf2f((u16)raw[j]);
        xq[ks][j] = x;
        ss += x*x;
      }
    }
    ss += __shfl_xor(ss, 16, 64);
    ss += __shfl_xor(ss, 32, 64);
    float rn = rsqrtf(ss*(1.0f/128.0f) + 1e-6f);
    const float* cp = cosb + (size_t)(b*2048 + srow)*128;
    const float* sp = sinb + (size_t)(b*2048 + srow)*128;
#pragma unroll
    for (int ks2=0;ks2<2;ks2++){
#pragma unroll
      for (int j=0;j<8;j++){
        int d0 = ks2*32 + hi*8 + j;               // in [0,64)
        int d1 = d0 + 64;
        float a  = xq[ks2][j]   * rn * qw[d0];
        float bb = xq[ks2+2][j] * rn * qw[d1];
        float o0 = a*cp[d0] - bb*sp[d0];
        float o1 = bb*cp[d1] + a*sp[d1];
        qf[ks2][j]   = (short)f2bf(o0);
        qf[ks2+2][j] = (short)f2bf(o1);
      }
    }
  }

  float lsum[4] = {0.f,0.f,0.f,0.f};

  // ---- sweep 1: denominators; quad-buffered K, counted waits, 1 barrier/tile ----
  // NOTE: the Q-norm's global loads above also count in vmcnt, but they are consumed
  // (waited on) by the compiler before qf is built, so outstanding ops here = staged K only.
  for (int t=0; t<nkt; ++t) {
    if      (t+2 < nkt) { asm volatile("s_waitcnt vmcnt(4)" ::: "memory"); }
    else if (t+1 < nkt) { asm volatile("s_waitcnt vmcnt(2)" ::: "memory"); }
    else                { asm volatile("s_waitcnt vmcnt(0)" ::: "memory"); }
    __syncthreads();
    if (t+3 < nkt) STAGE_K8(t+3, lKV[(t+3)&3]);
    asm volatile("" ::: "memory");
    if (t <= tdiag) {
      f32x4 sacc[4];
#pragma unroll
      for (int ns=0;ns<4;ns++) sacc[ns] = zero4;
      COMPUTE_S16(sacc, lKV[t&3]);
      const int cb = t*64 + rl;
      if (t == tdiag) {
#pragma unroll
        for (int ns=0;ns<4;ns++)
#pragma unroll
          for (int r=0;r<4;r++){
            int rg = rb + r, cg = cb + ns*16;
            float e = __builtin_exp2f(sacc[ns][r]*SCALE_LOG2E);
            lsum[r] += (cg <= rg) ? e : 0.f;
          }
      } else {
#pragma unroll
        for (int ns=0;ns<4;ns++)
#pragma unroll
          for (int r=0;r<4;r++)
            lsum[r] += __builtin_exp2f(sacc[ns][r]*SCALE_LOG2E);
      }
    }
  }
#pragma unroll
  for (int m=1;m<16;m<<=1)
#pragma unroll
    for (int r=0;r<4;r++) lsum[r] += __shfl_xor(lsum[r], m, 64);
  float Lr[4];
#pragma unroll
  for (int r=0;r<4;r++) Lr[r] = -__log2f(lsum[r]);   // fold 1/lsum into exp2 addend

  // ---- sweep 2: probs + PV; dbuf K+V, counted ledger (4 loads + 4 vec stores/tile) ----
  f32x4 oacc[8];
#pragma unroll
  for (int nd=0;nd<8;nd++) oacc[nd] = zero4;

  u16* pw = lP[wv];
  float* pb = probs + (size_t)bh*2048*2048;

  int cur = 0;
  STAGE_K8(0, lKV[0]);
  STAGE_V8(0, lKV[2]);
  asm volatile("s_waitcnt vmcnt(0)" ::: "memory");
  __syncthreads();
  for (int t=0; t<nkt; ++t) {
    const bool pf = (t+1 < nkt);
    if (pf) { STAGE_K8(t+1, lKV[cur^1]); STAGE_V8(t+1, lKV[2+(cur^1)]); }
    asm volatile("" ::: "memory");   // pin staging loads ahead of prob stores (vmcnt FIFO)
    if (t <= tdiag) {
      f32x4 sacc[4];
#pragma unroll
      for (int ns=0;ns<4;ns++) sacc[ns] = zero4;
      COMPUTE_S16(sacc, lKV[cur]);
      const int cb = t*64 + rl;
      if (t == tdiag) {
#pragma unroll
        for (int ns=0;ns<4;ns++)
#pragma unroll
          for (int r=0;r<4;r++){
            int rg = rb + r, cg = cb + ns*16;
            float p = (cg <= rg) ? __builtin_exp2f(fmaf(sacc[ns][r], SCALE_LOG2E, Lr[r])) : 0.f;
            int ql = hi*4 + r, kl = ns*16 + rl;
            pw[ql*64 + (((kl>>3) ^ (ql&7))<<3) + (kl&7)] = f2bf_trunc(p);
          }
      } else {
#pragma unroll
        for (int ns=0;ns<4;ns++)
#pragma unroll
          for (int r=0;r<4;r++){
            float p = __builtin_exp2f(fmaf(sacc[ns][r], SCALE_LOG2E, Lr[r]));
            int ql = hi*4 + r, kl = ns*16 + rl;
            pw[ql*64 + (((kl>>3) ^ (ql&7))<<3) + (kl&7)] = f2bf_trunc(p);
          }
      }
      // vectorized prob store: read back rows from lP, 4 x dwordx4 nontemporal
      {
        const int cq = rl, grp = cq>>1, off = (cq&1)*4;
#pragma unroll
        for (int it=0; it<4; ++it){
          int row = it*4 + hi;
          int slot = grp ^ (row&7);
          u16x4 pk4 = *(const u16x4*)(pw + row*64 + slot*8 + off);
          f32x4 pf4;
#pragma unroll
          for (int r=0;r<4;r++) pf4[r] = bf2f(pk4[r]);
          __builtin_nontemporal_store(pf4,
            (f32x4*)(pb + (size_t)(q0 + wv*16 + row)*2048 + t*64 + cq*4));
        }
      }
      // PV from lKV[2+cur]
      const u16* vbuf = lKV[2+cur];
#pragma unroll
      for (int kks=0;kks<2;kks++){
        bf16x8 pa;
        {
          int ql = rl;
          int sl = (kks*4 + hi) ^ (ql&7);
          pa = *(const bf16x8*)(pw + ql*64 + sl*8);
        }
#pragma unroll
        for (int nd=0;nd<8;nd++){
          int d = nd*16 + rl;
          int sl = (kks*4 + hi) ^ (d&7);
          bf16x8 vb = *(const bf16x8*)(vbuf + d*64 + sl*8);
          oacc[nd] = __builtin_amdgcn_mfma_f32_16x16x32_bf16(pa, vb, oacc[nd], 0,0,0);
        }
      }
    }
    if (pf) {
      asm volatile("s_waitcnt vmcnt(4)" ::: "memory");
      __syncthreads();
    }
    cur ^= 1;
  }

  // zero-fill strictly-above-diagonal region for this wave's rows
  const int kend = (tdiag+1)*64;
  f32x4 z4 = {0.f,0.f,0.f,0.f};
  for (int q = wv*16; q < wv*16+16; ++q){
    float* rp = pb + (size_t)(q0 + q)*2048;
    for (int c = kend + lane*4; c < 2048; c += 256)
      __builtin_nontemporal_store(z4, (f32x4*)(rp + c));
  }

  // write O (bf16) to workspace in (b, s, h*128+d) layout for the Wo GEMM
#pragma unroll
  for (int nd=0;nd<8;nd++)
#pragma unroll
    for (int r=0;r<4;r++){
      int rg = rb + r;
      int cg = h*128 + nd*16 + rl;
      attn_o[(size_t)(b*2048 + rg)*2048 + cg] = f2bf(oacc[nd][r]);
    }
}

// ---------------- host launch ----------------
extern "C" void kernel_launch(void* const* d_in, const int* in_sizes, int n_in,
                              void* d_out, int out_size, void* d_ws, size_t ws_size,
                              hipStream_t stream) {
  (void)in_sizes; (void)n_in; (void)out_size; (void)ws_size;
  const float* hs   = (const float*)d_in[0];
  const float* cosb = (const float*)d_in[1];
  const float* sinb = (const float*)d_in[2];
  const float* Wq   = (const float*)d_in[4];
  const float* Wk   = (const float*)d_in[5];
  const float* Wv   = (const float*)d_in[6];
  const float* Wo   = (const float*)d_in[7];
  const float* qw   = (const float*)d_in[8];
  const float* kw   = (const float*)d_in[9];
  float* out   = (float*)d_out;
  float* probs = out + 8388608;          // attn_output is 2*2048*2048 floats

  char* ws = (char*)d_ws;
  u16* hs_b   = (u16*)(ws);               // 16 MiB   (aliased: reused as attn_o)
  u16* attn_o = hs_b;
  u16* W_all  = (u16*)(ws + (16u<<20));   // 16 MiB   Wq|Wk|Wv rows (4096 x 2048)
  u16* Wo_b   = (u16*)(ws + (32u<<20));   // 8 MiB
  u16* qkv    = (u16*)(ws + (40u<<20));   // 32 MiB   (4096 x 4096)
  u16* v_t    = (u16*)(ws + (72u<<20));   // 8 MiB    (2*8*128 x 2048)

  k_cvt5<<<20480,256,0,stream>>>(hs, hs_b, Wq, W_all, Wk, W_all + 4194304,
                                 Wv, W_all + 6291456, Wo, Wo_b);

  k_gemm256<<<256,512,0,stream>>>(hs_b, W_all, (void*)qkv, 4096, 2048, 4096, 0);
  k_prep<<<9216,256,0,stream>>>(qkv, v_t, cosb, sinb, kw);
  k_attn<<<512,512,0,stream>>>(qkv, v_t, cosb, sinb, qw, probs, attn_o);
  k_gemm_bm128<<<256,512,0,stream>>>(attn_o, Wo_b, out, 2048, 2048, 2048);
}